// Round 1
// baseline (147.153 us; speedup 1.0000x reference)
//
#include <hip/hip_runtime.h>

// Problem constants
#define BB 8192
#define CC 4096
#define GG 16
#define SS 256
#define RR 512
#define NN (GG*RR)   // 8192 output cols

typedef __bf16 bf16x8 __attribute__((ext_vector_type(8)));
typedef float  f32x4_t __attribute__((ext_vector_type(4)));

__device__ __forceinline__ unsigned short f2bf(float f){
  union{float f; unsigned int u;} v; v.f = f;
  unsigned int r = (v.u + 0x7FFFu + ((v.u>>16)&1u)) >> 16;
  return (unsigned short)r;
}

__device__ __forceinline__ void gld_lds16(const void* g, void* l){
  __builtin_amdgcn_global_load_lds((const __attribute__((address_space(1))) void*)g,
                                   (__attribute__((address_space(3))) void*)l, 16, 0, 0);
}

// ---------------- Pass 1a: per-row gather + f32->bf16 cast ----------------
// One block per row of x. Stage row in LDS (coalesced), gather via LDS.
__global__ void __launch_bounds__(256) permute_cast_kernel(
    const float* __restrict__ x, const int* __restrict__ perm,
    unsigned short* __restrict__ xp)
{
  __shared__ float row[CC];
  const int tid = threadIdx.x;
  const size_t b = blockIdx.x;
  const float4* xr = (const float4*)(x + b*CC);
  float4* rr = (float4*)row;
  #pragma unroll
  for (int c=0;c<4;++c) rr[c*256+tid] = xr[c*256+tid];
  __syncthreads();
  unsigned short* xo = xp + b*CC;
  #pragma unroll
  for (int c=0;c<2;++c){
    const int j0 = (((c<<8)+tid)<<3);
    const int* pp = perm + j0;
    unsigned int w0 = (unsigned)f2bf(row[pp[0]]) | ((unsigned)f2bf(row[pp[1]])<<16);
    unsigned int w1 = (unsigned)f2bf(row[pp[2]]) | ((unsigned)f2bf(row[pp[3]])<<16);
    unsigned int w2 = (unsigned)f2bf(row[pp[4]]) | ((unsigned)f2bf(row[pp[5]])<<16);
    unsigned int w3 = (unsigned)f2bf(row[pp[6]]) | ((unsigned)f2bf(row[pp[7]])<<16);
    uint4 o; o.x=w0; o.y=w1; o.z=w2; o.w=w3;
    *(uint4*)(xo + j0) = o;
  }
}

// ---------------- Pass 1b: W f32->bf16 cast ----------------
__global__ void __launch_bounds__(256) cast_w_kernel(
    const float* __restrict__ W, unsigned short* __restrict__ Wb)
{
  const int i = (blockIdx.x*256 + threadIdx.x)<<3;
  float4 f0 = ((const float4*)(W+i))[0];
  float4 f1 = ((const float4*)(W+i))[1];
  uint4 o;
  o.x = (unsigned)f2bf(f0.x) | ((unsigned)f2bf(f0.y)<<16);
  o.y = (unsigned)f2bf(f0.z) | ((unsigned)f2bf(f0.w)<<16);
  o.z = (unsigned)f2bf(f1.x) | ((unsigned)f2bf(f1.y)<<16);
  o.w = (unsigned)f2bf(f1.z) | ((unsigned)f2bf(f1.w)<<16);
  *(uint4*)(Wb+i) = o;
}

// ---------------- Pass 2: grouped GEMM, 128x128 tile, K=256 ----------------
// out[m][n] = sum_k xp[m][g*256+k] * Wb[n*256+k] + bias[n],  g = n/512
__global__ void __launch_bounds__(256) gemm_kernel(
    const unsigned short* __restrict__ xp, const unsigned short* __restrict__ Wb,
    const float* __restrict__ bias, float* __restrict__ out)
{
  __shared__ unsigned short lA[128*64];
  __shared__ unsigned short lB[128*64];
  const int tid  = threadIdx.x;
  const int lane = tid & 63;
  const int w    = tid >> 6;
  const int wr   = w >> 1, wc = w & 1;
  const int l15  = lane & 15, lh = lane >> 4;
  const int bx = blockIdx.x, by = blockIdx.y;
  const int m0 = by << 7;
  const int n0 = bx << 7;
  const int g  = bx >> 2;                 // 512/128 = 4 n-tiles per group
  const size_t arow0 = (size_t)m0*CC + (size_t)g*SS;
  const size_t brow0 = (size_t)n0*SS;

  f32x4_t acc[4][4];
  for (int i=0;i<4;++i)
    for (int j=0;j<4;++j)
      acc[i][j] = (f32x4_t){0.f,0.f,0.f,0.f};

  for (int kk=0; kk<SS; kk+=64){
    #pragma unroll
    for (int c=0;c<4;++c){
      const int i  = (c<<8) + tid;     // 16B chunk index 0..1023
      const int r  = i>>3;             // tile row 0..127
      const int cc = (i&7)<<3;         // bf16 col offset within 64
      gld_lds16(xp + arow0 + (size_t)r*CC + kk + cc, &lA[i<<3]);
      gld_lds16(Wb + brow0 + (size_t)r*SS + kk + cc, &lB[i<<3]);
    }
    __syncthreads();
    #pragma unroll
    for (int ks=0;ks<2;++ks){
      bf16x8 af[4], bfr[4];
      #pragma unroll
      for (int mi=0;mi<4;++mi)
        af[mi]  = *(const bf16x8*)&lA[((wr<<6)+(mi<<4)+l15)*64 + (ks<<5) + (lh<<3)];
      #pragma unroll
      for (int ni=0;ni<4;++ni)
        bfr[ni] = *(const bf16x8*)&lB[((wc<<6)+(ni<<4)+l15)*64 + (ks<<5) + (lh<<3)];
      #pragma unroll
      for (int mi=0;mi<4;++mi){
        #pragma unroll
        for (int ni=0;ni<4;++ni)
          acc[mi][ni] = __builtin_amdgcn_mfma_f32_16x16x32_bf16(af[mi], bfr[ni], acc[mi][ni], 0,0,0);
      }
    }
    __syncthreads();
  }

  // Epilogue: bias add + store. D layout: col=lane&15, row=(lane>>4)*4+reg.
  #pragma unroll
  for (int ni=0;ni<4;++ni){
    const int col = n0 + (wc<<6) + (ni<<4) + l15;
    const float bv = bias[col];
    #pragma unroll
    for (int mi=0;mi<4;++mi){
      const int rb = m0 + (wr<<6) + (mi<<4) + (lh<<2);
      float* op = out + (size_t)rb*NN + col;
      #pragma unroll
      for (int r=0;r<4;++r)
        op[(size_t)r*NN] = acc[mi][ni][r] + bv;
    }
  }
}

extern "C" void kernel_launch(void* const* d_in, const int* in_sizes, int n_in,
                              void* d_out, int out_size, void* d_ws, size_t ws_size,
                              hipStream_t stream) {
  const float* x    = (const float*)d_in[0];   // [B, C] f32
  const float* W    = (const float*)d_in[1];   // [G, R, S] f32
  const float* bias = (const float*)d_in[2];   // [G, R] f32
  const int*   perm = (const int*)d_in[3];     // [G, S] int32
  float* out = (float*)d_out;                  // [B, G*R] f32

  unsigned short* xp = (unsigned short*)d_ws;                       // B*C bf16 = 64 MiB
  unsigned short* Wb = (unsigned short*)((char*)d_ws + (size_t)BB*CC*2); // G*R*S bf16 = 4 MiB

  permute_cast_kernel<<<dim3(BB), dim3(256), 0, stream>>>(x, perm, xp);
  cast_w_kernel<<<dim3((GG*RR*SS)/(256*8)), dim3(256), 0, stream>>>(W, Wb);
  gemm_kernel<<<dim3(NN/128, BB/128), dim3(256), 0, stream>>>(xp, Wb, bias, out);
}

// Round 2
// 137.071 us; speedup vs baseline: 1.0736x; 1.0736x over previous
//
#include <hip/hip_runtime.h>

// Problem constants
#define BB 8192
#define CC 4096
#define GG 16
#define SS 256
#define RR 512
#define NN (GG*RR)   // 8192 output cols

typedef __bf16 bf16x8 __attribute__((ext_vector_type(8)));
typedef float  f32x4_t __attribute__((ext_vector_type(4)));

__device__ __forceinline__ unsigned short f2bf(float f){
  union{float f; unsigned int u;} v; v.f = f;
  unsigned int r = (v.u + 0x7FFFu + ((v.u>>16)&1u)) >> 16;
  return (unsigned short)r;
}

__device__ __forceinline__ void gld_lds16(const void* g, void* l){
  __builtin_amdgcn_global_load_lds((const __attribute__((address_space(1))) void*)g,
                                   (__attribute__((address_space(3))) void*)l, 16, 0, 0);
}

// ---------------- Pass 1a: per-row gather + f32->bf16 cast ----------------
__global__ void __launch_bounds__(256) permute_cast_kernel(
    const float* __restrict__ x, const int* __restrict__ perm,
    unsigned short* __restrict__ xp)
{
  __shared__ float row[CC];
  const int tid = threadIdx.x;
  const size_t b = blockIdx.x;
  const float4* xr = (const float4*)(x + b*CC);
  float4* rr = (float4*)row;
  #pragma unroll
  for (int c=0;c<4;++c) rr[c*256+tid] = xr[c*256+tid];
  __syncthreads();
  unsigned short* xo = xp + b*CC;
  #pragma unroll
  for (int c=0;c<2;++c){
    const int j0 = (((c<<8)+tid)<<3);
    const int* pp = perm + j0;
    unsigned int w0 = (unsigned)f2bf(row[pp[0]]) | ((unsigned)f2bf(row[pp[1]])<<16);
    unsigned int w1 = (unsigned)f2bf(row[pp[2]]) | ((unsigned)f2bf(row[pp[3]])<<16);
    unsigned int w2 = (unsigned)f2bf(row[pp[4]]) | ((unsigned)f2bf(row[pp[5]])<<16);
    unsigned int w3 = (unsigned)f2bf(row[pp[6]]) | ((unsigned)f2bf(row[pp[7]])<<16);
    uint4 o; o.x=w0; o.y=w1; o.z=w2; o.w=w3;
    *(uint4*)(xo + j0) = o;
  }
}

// ---------------- Pass 1b: W f32->bf16 cast ----------------
__global__ void __launch_bounds__(256) cast_w_kernel(
    const float* __restrict__ W, unsigned short* __restrict__ Wb)
{
  const int i = (blockIdx.x*256 + threadIdx.x)<<3;
  float4 f0 = ((const float4*)(W+i))[0];
  float4 f1 = ((const float4*)(W+i))[1];
  uint4 o;
  o.x = (unsigned)f2bf(f0.x) | ((unsigned)f2bf(f0.y)<<16);
  o.y = (unsigned)f2bf(f0.z) | ((unsigned)f2bf(f0.w)<<16);
  o.z = (unsigned)f2bf(f1.x) | ((unsigned)f2bf(f1.y)<<16);
  o.w = (unsigned)f2bf(f1.z) | ((unsigned)f2bf(f1.w)<<16);
  *(uint4*)(Wb+i) = o;
}

// ---------------- Pass 2: grouped GEMM, 128x128 tile, K=256 ----------------
// out[m][n] = sum_k xp[m][g*256+k] * Wb[n*256+k] + bias[n],  g = n/512
// T2: LDS XOR-swizzle (chunkcol ^= row&7), linear gld_lds dest + pre-swizzled
//     global source + swizzled ds_read (rule 21).
// T1: 1D grid, XCD-bijective map; each XCD owns 2 groups (bx range of 8).
__global__ void __launch_bounds__(256) gemm_kernel(
    const unsigned short* __restrict__ xp, const unsigned short* __restrict__ Wb,
    const float* __restrict__ bias, float* __restrict__ out)
{
  __shared__ unsigned short lA[128*64];
  __shared__ unsigned short lB[128*64];
  const int tid  = threadIdx.x;
  const int lane = tid & 63;
  const int w    = tid >> 6;
  const int wr   = w >> 1, wc = w & 1;
  const int l15  = lane & 15, lh = lane >> 4;

  // XCD-aware block mapping: nwg=4096, 512 per XCD, bx-major chunks of 8.
  const int bid   = blockIdx.x;
  const int xcd   = bid & 7;
  const int local = bid >> 3;           // 0..511
  const int bx    = (xcd << 3) + (local & 7);   // 8 n-tiles = 2 groups per XCD
  const int by    = local >> 3;         // 0..63

  const int m0 = by << 7;
  const int n0 = bx << 7;
  const int g  = bx >> 2;
  const size_t arow0 = (size_t)m0*CC + (size_t)g*SS;
  const size_t brow0 = (size_t)n0*SS;

  f32x4_t acc[4][4];
  for (int i=0;i<4;++i)
    for (int j=0;j<4;++j)
      acc[i][j] = (f32x4_t){0.f,0.f,0.f,0.f};

  for (int kk=0; kk<SS; kk+=64){
    #pragma unroll
    for (int c=0;c<4;++c){
      const int i  = (c<<8) + tid;         // 16B chunk index 0..1023
      const int r  = i>>3;                 // tile row 0..127
      const int cs = ((i&7) ^ (r&7)) << 3; // pre-swizzled source bf16 col
      gld_lds16(xp + arow0 + (size_t)r*CC + kk + cs, &lA[i<<3]);
      gld_lds16(Wb + brow0 + (size_t)r*SS + kk + cs, &lB[i<<3]);
    }
    __syncthreads();
    #pragma unroll
    for (int ks=0;ks<2;++ks){
      bf16x8 af[4], bfr[4];
      const int cc = (ks<<2) + lh;        // logical 16B chunk col 0..7
      #pragma unroll
      for (int mi=0;mi<4;++mi){
        const int ar = (wr<<6)+(mi<<4)+l15;
        af[mi]  = *(const bf16x8*)&lA[ar*64 + ((cc ^ (ar&7))<<3)];
      }
      #pragma unroll
      for (int ni=0;ni<4;++ni){
        const int br = (wc<<6)+(ni<<4)+l15;
        bfr[ni] = *(const bf16x8*)&lB[br*64 + ((cc ^ (br&7))<<3)];
      }
      #pragma unroll
      for (int mi=0;mi<4;++mi){
        #pragma unroll
        for (int ni=0;ni<4;++ni)
          acc[mi][ni] = __builtin_amdgcn_mfma_f32_16x16x32_bf16(af[mi], bfr[ni], acc[mi][ni], 0,0,0);
      }
    }
    __syncthreads();
  }

  // Epilogue: bias add + store. D layout: col=lane&15, row=(lane>>4)*4+reg.
  #pragma unroll
  for (int ni=0;ni<4;++ni){
    const int col = n0 + (wc<<6) + (ni<<4) + l15;
    const float bv = bias[col];
    #pragma unroll
    for (int mi=0;mi<4;++mi){
      const int rb = m0 + (wr<<6) + (mi<<4) + (lh<<2);
      float* op = out + (size_t)rb*NN + col;
      #pragma unroll
      for (int r=0;r<4;++r)
        op[(size_t)r*NN] = acc[mi][ni][r] + bv;
    }
  }
}

extern "C" void kernel_launch(void* const* d_in, const int* in_sizes, int n_in,
                              void* d_out, int out_size, void* d_ws, size_t ws_size,
                              hipStream_t stream) {
  const float* x    = (const float*)d_in[0];   // [B, C] f32
  const float* W    = (const float*)d_in[1];   // [G, R, S] f32
  const float* bias = (const float*)d_in[2];   // [G, R] f32
  const int*   perm = (const int*)d_in[3];     // [G, S] int32
  float* out = (float*)d_out;                  // [B, G*R] f32

  unsigned short* xp = (unsigned short*)d_ws;                            // B*C bf16 = 64 MiB
  unsigned short* Wb = (unsigned short*)((char*)d_ws + (size_t)BB*CC*2); // G*R*S bf16 = 4 MiB

  permute_cast_kernel<<<dim3(BB), dim3(256), 0, stream>>>(x, perm, xp);
  cast_w_kernel<<<dim3((GG*RR*SS)/(256*8)), dim3(256), 0, stream>>>(W, Wb);
  gemm_kernel<<<dim3(4096), dim3(256), 0, stream>>>(xp, Wb, bias, out);
}

// Round 3
// 123.846 us; speedup vs baseline: 1.1882x; 1.1068x over previous
//
#include <hip/hip_runtime.h>

// Problem constants
#define BB 8192
#define CC 4096
#define GG 16
#define SS 256
#define RR 512
#define NN (GG*RR)   // 8192 output cols

typedef __bf16 bf16x8 __attribute__((ext_vector_type(8)));
typedef float  f32x4_t __attribute__((ext_vector_type(4)));

__device__ __forceinline__ unsigned short f2bf(float f){
  union{float f; unsigned int u;} v; v.f = f;
  unsigned int r = (v.u + 0x7FFFu + ((v.u>>16)&1u)) >> 16;
  return (unsigned short)r;
}

__device__ __forceinline__ void gld_lds16(const void* g, void* l){
  __builtin_amdgcn_global_load_lds((const __attribute__((address_space(1))) void*)g,
                                   (__attribute__((address_space(3))) void*)l, 16, 0, 0);
}

// ---------------- Pass 1: fused {per-row gather+cast} and {W cast} ----------
// Blocks 0..BB-1: permute+cast one x row. Blocks BB..BB+1023: cast W chunk.
__global__ void __launch_bounds__(256) prep_kernel(
    const float* __restrict__ x, const int* __restrict__ perm,
    const float* __restrict__ W,
    unsigned short* __restrict__ xp, unsigned short* __restrict__ Wb)
{
  __shared__ float row[CC];
  const int tid = threadIdx.x;
  const int bid = blockIdx.x;
  if (bid < BB) {
    const size_t b = bid;
    const float4* xr = (const float4*)(x + b*CC);
    float4* rr = (float4*)row;
    #pragma unroll
    for (int c=0;c<4;++c) rr[c*256+tid] = xr[c*256+tid];
    __syncthreads();
    unsigned short* xo = xp + b*CC;
    #pragma unroll
    for (int c=0;c<2;++c){
      const int j0 = (((c<<8)+tid)<<3);
      const int* pp = perm + j0;
      unsigned int w0 = (unsigned)f2bf(row[pp[0]]) | ((unsigned)f2bf(row[pp[1]])<<16);
      unsigned int w1 = (unsigned)f2bf(row[pp[2]]) | ((unsigned)f2bf(row[pp[3]])<<16);
      unsigned int w2 = (unsigned)f2bf(row[pp[4]]) | ((unsigned)f2bf(row[pp[5]])<<16);
      unsigned int w3 = (unsigned)f2bf(row[pp[6]]) | ((unsigned)f2bf(row[pp[7]])<<16);
      uint4 o; o.x=w0; o.y=w1; o.z=w2; o.w=w3;
      *(uint4*)(xo + j0) = o;
    }
  } else {
    const int i = (((bid - BB)<<8) + tid)<<3;
    float4 f0 = ((const float4*)(W+i))[0];
    float4 f1 = ((const float4*)(W+i))[1];
    uint4 o;
    o.x = (unsigned)f2bf(f0.x) | ((unsigned)f2bf(f0.y)<<16);
    o.y = (unsigned)f2bf(f0.z) | ((unsigned)f2bf(f0.w)<<16);
    o.z = (unsigned)f2bf(f1.x) | ((unsigned)f2bf(f1.y)<<16);
    o.w = (unsigned)f2bf(f1.z) | ((unsigned)f2bf(f1.w)<<16);
    *(uint4*)(Wb+i) = o;
  }
}

// ---------------- Pass 2: grouped GEMM, 128x128 tile, K=256 -----------------
// 8 waves (2 row x 4 col), double-buffered LDS, counted vmcnt (T4),
// LDS XOR-swizzle (T2, both-sides), XCD-bijective block map (T1).
__global__ void __launch_bounds__(512, 4) gemm_kernel(
    const unsigned short* __restrict__ xp, const unsigned short* __restrict__ Wb,
    const float* __restrict__ bias, float* __restrict__ out)
{
  __shared__ unsigned short lA[2][128*64];
  __shared__ unsigned short lB[2][128*64];
  const int tid  = threadIdx.x;
  const int lane = tid & 63;
  const int w    = tid >> 6;
  const int wr   = w >> 2;          // 0..1  (64 out rows each)
  const int wc   = w & 3;           // 0..3  (32 out cols each)
  const int l15  = lane & 15, lh = lane >> 4;

  // XCD-aware block mapping: nwg=4096, 512 per XCD, bx-octet per XCD.
  const int bid   = blockIdx.x;
  const int xcd   = bid & 7;
  const int local = bid >> 3;                   // 0..511
  const int bx    = (xcd << 3) + (local & 7);   // 8 n-tiles = 2 groups per XCD
  const int by    = local >> 3;                 // 0..63

  const int m0 = by << 7;
  const int n0 = bx << 7;
  const int g  = bx >> 2;
  const size_t arow0 = (size_t)m0*CC + (size_t)g*SS;
  const size_t brow0 = (size_t)n0*SS;

  f32x4_t acc[4][2];
  #pragma unroll
  for (int i=0;i<4;++i)
    #pragma unroll
    for (int j=0;j<2;++j)
      acc[i][j] = (f32x4_t){0.f,0.f,0.f,0.f};

  // Stage one 128x64 A-tile + 128x64 B-tile into buf (4 gld_lds16 / thread).
  auto STAGE = [&](int kk, int buf){
    #pragma unroll
    for (int c=0;c<2;++c){
      const int i  = (c<<9) + tid;           // 16B chunk 0..1023
      const int r  = i>>3;
      const int cs = ((i&7) ^ (r&7)) << 3;   // pre-swizzled source col (T2)
      gld_lds16(xp + arow0 + (size_t)r*CC + kk + cs, &lA[buf][i<<3]);
    }
    #pragma unroll
    for (int c=0;c<2;++c){
      const int i  = (c<<9) + tid;
      const int r  = i>>3;
      const int cs = ((i&7) ^ (r&7)) << 3;
      gld_lds16(Wb + brow0 + (size_t)r*SS + kk + cs, &lB[buf][i<<3]);
    }
  };

  auto COMPUTE = [&](int buf){
    #pragma unroll
    for (int ks=0;ks<2;++ks){
      bf16x8 af[4], bfr[2];
      const int cc = (ks<<2) + lh;           // logical 16B chunk col 0..7
      #pragma unroll
      for (int mi=0;mi<4;++mi){
        const int ar = (wr<<6)+(mi<<4)+l15;
        af[mi]  = *(const bf16x8*)&lA[buf][ar*64 + ((cc ^ (ar&7))<<3)];
      }
      #pragma unroll
      for (int ni=0;ni<2;++ni){
        const int br = (wc<<5)+(ni<<4)+l15;
        bfr[ni] = *(const bf16x8*)&lB[buf][br*64 + ((cc ^ (br&7))<<3)];
      }
      #pragma unroll
      for (int mi=0;mi<4;++mi)
        #pragma unroll
        for (int ni=0;ni<2;++ni)
          acc[mi][ni] = __builtin_amdgcn_mfma_f32_16x16x32_bf16(af[mi], bfr[ni], acc[mi][ni], 0,0,0);
    }
  };

  // Prologue: both buffers' loads in flight (8 outstanding / thread).
  STAGE(0, 0);
  STAGE(64, 1);
  #pragma unroll
  for (int t=0;t<4;++t){
    if (t<3) asm volatile("s_waitcnt vmcnt(4)" ::: "memory");
    else     asm volatile("s_waitcnt vmcnt(0)" ::: "memory");
    __builtin_amdgcn_s_barrier();     // buf[t&1] fully landed (all waves)
    COMPUTE(t&1);
    __builtin_amdgcn_s_barrier();     // all waves done reading buf[t&1]
    if (t<2) STAGE((t+2)<<6, t&1);    // overwrite now-free buffer
  }

  // Epilogue: bias add + store. D layout: col=lane&15, row=(lane>>4)*4+reg.
  #pragma unroll
  for (int ni=0;ni<2;++ni){
    const int col = n0 + (wc<<5) + (ni<<4) + l15;
    const float bv = bias[col];
    #pragma unroll
    for (int mi=0;mi<4;++mi){
      const int rb = m0 + (wr<<6) + (mi<<4) + (lh<<2);
      float* op = out + (size_t)rb*NN + col;
      #pragma unroll
      for (int r=0;r<4;++r)
        op[(size_t)r*NN] = acc[mi][ni][r] + bv;
    }
  }
}

extern "C" void kernel_launch(void* const* d_in, const int* in_sizes, int n_in,
                              void* d_out, int out_size, void* d_ws, size_t ws_size,
                              hipStream_t stream) {
  const float* x    = (const float*)d_in[0];   // [B, C] f32
  const float* W    = (const float*)d_in[1];   // [G, R, S] f32
  const float* bias = (const float*)d_in[2];   // [G, R] f32
  const int*   perm = (const int*)d_in[3];     // [G, S] int32
  float* out = (float*)d_out;                  // [B, G*R] f32

  unsigned short* xp = (unsigned short*)d_ws;                            // B*C bf16 = 64 MiB
  unsigned short* Wb = (unsigned short*)((char*)d_ws + (size_t)BB*CC*2); // G*R*S bf16 = 4 MiB

  const int wblocks = (GG*RR*SS)/(256*8);      // 1024
  prep_kernel<<<dim3(BB + wblocks), dim3(256), 0, stream>>>(x, perm, W, xp, Wb);
  gemm_kernel<<<dim3(4096), dim3(512), 0, stream>>>(xp, Wb, bias, out);
}